// Round 6
// baseline (530.736 us; speedup 1.0000x reference)
//
#include <hip/hip_runtime.h>

// Problem constants
constexpr int B_N = 4;
constexpr int C_N = 3;
constexpr int H_IMG = 720;
constexpr int W_IMG = 1280;
constexpr int HW = H_IMG * W_IMG;
// KERNEL_RADIUS=4, KERNEL_SIGMA2=0.5 -> w = exp(-d2)

// Gather tiling: block owns 64x64 targets; thread owns 8x (x) * 2 (y) targets.
constexpr int TW = 64, TH = 64;
constexpr int HALO = 7;                 // R(4) + flow slack (3.5)
constexpr int CW = TW + 2 * HALO;       // 78
constexpr int CH = TH + 2 * HALO;       // 78
constexpr int PITCH = 80;               // even: cell pairs are 4B-aligned in f16 planes
constexpr int PLANE = CH * PITCH;       // 6240 halfs/plane; 5 planes = 62.4 KB
constexpr float FLOW_MAX = 3.5f;
constexpr float LOG2E = 1.44269504f;
constexpr float MARKER = -30.0f;        // all weights underflow to 0, all temps finite

// e^{-1}, e^{-3}, e^{-5}, e^{-7} for the G^delta chain
#define K1 0.36787944117144233f
#define K3 0.049787068367863944f
#define K5 0.006737946999085467f
#define K7 0.0009118819655545162f

typedef _Float16 h2 __attribute__((ext_vector_type(2)));
#define PKRTZ(a, b) __builtin_bit_cast(h2, __builtin_amdgcn_cvt_pkrtz((a), (b)))

__global__ __launch_bounds__(256, 2)
void gather_kernel(const float* __restrict__ src, const float* __restrict__ flow,
                   float* __restrict__ out, int* __restrict__ olist, int ocap) {
    __shared__ _Float16 Up[PLANE], Vp[PLANE], P0[PLANE], P1[PLANE], P2[PLANE];

    const int b = blockIdx.z;
    const int tx0 = blockIdx.x * TW;
    const int ty0 = blockIdx.y * TH;
    const int cx0 = tx0 - HALO, cy0 = ty0 - HALO;

    const float* __restrict__ up = flow + (size_t)(b * 2) * HW;
    const float* __restrict__ vp = up + HW;
    const float* __restrict__ sp = src + (size_t)(b * 3) * HW;

    // Stage coverage as 5 separate f16 planes. Invalid/outlier cells -> MARKER.
    // Own-tile outliers are appended to the compact list (exactly-once).
    for (int idx = threadIdx.x; idx < CH * CW; idx += 256) {
        const int cr = idx / CW, cx = idx - cr * CW;
        const int gx = cx0 + cx, gy = cy0 + cr;
        float u = MARKER, v = MARKER, s0 = 0.f, s1 = 0.f, s2 = 0.f;
        if (gx >= 0 && gx < W_IMG && gy >= 0 && gy < H_IMG) {
            const int g = gy * W_IMG + gx;
            const float uu = up[g], vv = vp[g];
            if (fabsf(uu) <= FLOW_MAX && fabsf(vv) <= FLOW_MAX) {
                u = uu; v = vv;
                s0 = sp[g]; s1 = sp[HW + g]; s2 = sp[2 * HW + g];
            } else if (cx >= HALO && cx < HALO + TW && cr >= HALO && cr < HALO + TH) {
                const int k = atomicAdd(olist, 1);
                if (k < ocap) { olist[4 + 2 * k] = b; olist[5 + 2 * k] = g; }
            }
        }
        const int l = cr * PITCH + cx;
        Up[l] = (_Float16)u; Vp[l] = (_Float16)v;
        P0[l] = (_Float16)s0; P1[l] = (_Float16)s1; P2[l] = (_Float16)s2;
    }
    __syncthreads();

    const int xg = threadIdx.x & 7;     // 8 x-groups of 8 targets
    const int yg = threadIdx.x >> 3;    // 32 row-pairs
    const int ty_a = ty0 + 2 * yg;

    float aW[2][8], a0[2][8], a1[2][8], a2[2][8];
#pragma unroll
    for (int j = 0; j < 2; ++j)
#pragma unroll
        for (int i = 0; i < 8; ++i) { aW[j][i] = 0.f; a0[j][i] = 0.f;
                                      a1[j][i] = 0.f; a2[j][i] = 0.f; }

    for (int oy = 0; oy < 16; ++oy) {
        const float Cy = (float)(oy - 7);
        const int lrow = (2 * yg + oy) * PITCH + 8 * xg;   // even
#pragma unroll
        for (int oxp = 0; oxp < 11; ++oxp) {               // 22 cells = 11 pairs
            const int l = lrow + 2 * oxp;
            const h2 u2 = *(const h2*)(Up + l);
            const h2 v2 = *(const h2*)(Vp + l);
            const h2 s02 = *(const h2*)(P0 + l);
            const h2 s12 = *(const h2*)(P1 + l);
            const h2 s22 = *(const h2*)(P2 + l);
            const float uA = (float)u2.x, uB = (float)u2.y;
            const float vA = (float)v2.x, vB = (float)v2.y;

            // ---- x weight chains (f32, per cell) ----
            const float dxA = uA + (float)(2 * oxp - 11);
            const float dxB = uB + (float)(2 * oxp - 10);
            const float aLA = dxA * LOG2E, aLB = dxB * LOG2E;
            const float EA = __builtin_amdgcn_exp2f(-(aLA * dxA));
            const float EB = __builtin_amdgcn_exp2f(-(aLB * dxB));
            const float gA = aLA + aLA, gB = aLB + aLB;
            const float GA = __builtin_amdgcn_exp2f(gA);
            const float GB = __builtin_amdgcn_exp2f(gB);
            const float GiA = __builtin_amdgcn_exp2f(-gA);
            const float GiB = __builtin_amdgcn_exp2f(-gB);

            float wA[8], wB[8];
            wA[4] = EA; wB[4] = EB;
            wA[5] = wA[4] * (GA * K1); wB[5] = wB[4] * (GB * K1);
            wA[6] = wA[5] * (GA * K3); wB[6] = wB[5] * (GB * K3);
            wA[7] = wA[6] * (GA * K5); wB[7] = wB[6] * (GB * K5);
            wA[3] = wA[4] * (GiA * K1); wB[3] = wB[4] * (GiB * K1);
            wA[2] = wA[3] * (GiA * K3); wB[2] = wB[3] * (GiB * K3);
            wA[1] = wA[2] * (GiA * K5); wB[1] = wB[2] * (GiB * K5);
            wA[0] = wA[1] * (GiA * K7); wB[0] = wB[1] * (GiB * K7);

            h2 w2[8];
#pragma unroll
            for (int i = 0; i < 8; ++i)
                w2[i] = PKRTZ(wA[i], wB[i]);

            // ---- y weights (rows a,b) per cell ----
            const float dyA = vA + Cy, dyB = vB + Cy;
            const float bLA = dyA * LOG2E, bLB = dyB * LOG2E;
            const float eyaA = __builtin_amdgcn_exp2f(-(bLA * dyA));
            const float eyaB = __builtin_amdgcn_exp2f(-(bLB * dyB));
            const float rkA = __builtin_amdgcn_exp2f(bLA + bLA) * K1;
            const float rkB = __builtin_amdgcn_exp2f(bLB + bLB) * K1;
            const float eybA = eyaA * rkA, eybB = eyaB * rkB;

            const h2 eya2 = PKRTZ(eyaA, eyaB);
            const h2 eyb2 = PKRTZ(eybA, eybB);
            const h2 z0a = s02 * eya2, z0b = s02 * eyb2;
            const h2 z1a = s12 * eya2, z1b = s12 * eyb2;
            const h2 z2a = s22 * eya2, z2b = s22 * eyb2;

#pragma unroll
            for (int i = 0; i < 8; ++i) {
                aW[0][i] = __builtin_amdgcn_fdot2(w2[i], eya2, aW[0][i], false);
                aW[1][i] = __builtin_amdgcn_fdot2(w2[i], eyb2, aW[1][i], false);
                a0[0][i] = __builtin_amdgcn_fdot2(w2[i], z0a, a0[0][i], false);
                a0[1][i] = __builtin_amdgcn_fdot2(w2[i], z0b, a0[1][i], false);
                a1[0][i] = __builtin_amdgcn_fdot2(w2[i], z1a, a1[0][i], false);
                a1[1][i] = __builtin_amdgcn_fdot2(w2[i], z1b, a1[1][i], false);
                a2[0][i] = __builtin_amdgcn_fdot2(w2[i], z2a, a2[0][i], false);
                a2[1][i] = __builtin_amdgcn_fdot2(w2[i], z2b, a2[1][i], false);
            }
        }
    }

    // Write raw accumulators; outlier scatter adds, finalize divides.
    float* __restrict__ wI = out;
    float* __restrict__ wb = out + (size_t)B_N * C_N * HW;
    const int gx0 = tx0 + 8 * xg;
#pragma unroll
    for (int j = 0; j < 2; ++j) {
        const int ty = ty_a + j;
        if (ty >= H_IMG) continue;
        const int tb = ty * W_IMG + gx0;              // 16B-aligned
        float* p0 = wI + (size_t)(b * 3 + 0) * HW + tb;
        float* p1 = wI + (size_t)(b * 3 + 1) * HW + tb;
        float* p2 = wI + (size_t)(b * 3 + 2) * HW + tb;
        float* pw = wb + (size_t)b * HW + tb;
        *(float4*)(p0)     = make_float4(a0[j][0], a0[j][1], a0[j][2], a0[j][3]);
        *(float4*)(p0 + 4) = make_float4(a0[j][4], a0[j][5], a0[j][6], a0[j][7]);
        *(float4*)(p1)     = make_float4(a1[j][0], a1[j][1], a1[j][2], a1[j][3]);
        *(float4*)(p1 + 4) = make_float4(a1[j][4], a1[j][5], a1[j][6], a1[j][7]);
        *(float4*)(p2)     = make_float4(a2[j][0], a2[j][1], a2[j][2], a2[j][3]);
        *(float4*)(p2 + 4) = make_float4(a2[j][4], a2[j][5], a2[j][6], a2[j][7]);
        *(float4*)(pw)     = make_float4(aW[j][0], aW[j][1], aW[j][2], aW[j][3]);
        *(float4*)(pw + 4) = make_float4(aW[j][4], aW[j][5], aW[j][6], aW[j][7]);
    }
}

// Exact splat for listed outlier sources (compact list built by gather).
__global__ __launch_bounds__(256)
void outlier_kernel(const float* __restrict__ src, const float* __restrict__ flow,
                    float* __restrict__ out, const int* __restrict__ olist, int ocap) {
    const int count = min(olist[0], ocap);
    float* __restrict__ wI = out;
    float* __restrict__ wb = out + (size_t)B_N * C_N * HW;
    for (int e = blockIdx.x * 256 + threadIdx.x; e < count; e += gridDim.x * 256) {
        const int b = olist[4 + 2 * e];
        const int g = olist[5 + 2 * e];
        const float* __restrict__ up = flow + (size_t)(b * 2) * HW;
        const float u = up[g], v = up[HW + g];
        const int x = g % W_IMG, y = g / W_IMG;
        const float px = (float)x + u, py = (float)y + v;
        if (!(px > -6.f && px < (float)W_IMG + 5.f &&
              py > -6.f && py < (float)H_IMG + 5.f)) continue;

        const float bxf = floorf(px), byf = floorf(py);
        const int bx = (int)bxf, by = (int)byf;
        const float* __restrict__ sp = src + (size_t)(b * 3) * HW;
        const float s0 = sp[g], s1 = sp[HW + g], s2 = sp[2 * HW + g];

        for (int dyi = -4; dyi <= 4; ++dyi) {
            const int tyy = by + dyi;
            if (tyy < 0 || tyy >= H_IMG) continue;
            const float dyf = (byf + (float)dyi) - py;
            const float dy2 = dyf * dyf;
            for (int dxi = -4; dxi <= 4; ++dxi) {
                const int txx = bx + dxi;
                if (txx < 0 || txx >= W_IMG) continue;
                const float dxf = (bxf + (float)dxi) - px;
                const float d2 = fmaf(dxf, dxf, dy2);
                if (d2 > 16.f) continue;
                const float w = __expf(-d2);
                const int t = tyy * W_IMG + txx;
                atomicAdd(&wb[(size_t)b * HW + t], w);
                atomicAdd(&wI[(size_t)(b * 3 + 0) * HW + t], w * s0);
                atomicAdd(&wI[(size_t)(b * 3 + 1) * HW + t], w * s1);
                atomicAdd(&wI[(size_t)(b * 3 + 2) * HW + t], w * s2);
            }
        }
    }
}

__global__ __launch_bounds__(256)
void finalize_kernel(float* __restrict__ out) {
    const int i = blockIdx.x * blockDim.x + threadIdx.x;
    const int n4 = B_N * HW / 4;
    if (i >= n4) return;
    const int per_b = HW / 4;
    const int b = i / per_b;
    const int hw = (i - b * per_b) * 4;
    float* __restrict__ wb = out + (size_t)B_N * C_N * HW + (size_t)b * HW + hw;
    float4 w = *(float4*)wb;
    const float4 inv = make_float4(1.f / (w.x + 1e-8f), 1.f / (w.y + 1e-8f),
                                   1.f / (w.z + 1e-8f), 1.f / (w.w + 1e-8f));
    float* base = out + (size_t)(b * 3) * HW + hw;
#pragma unroll
    for (int c = 0; c < 3; ++c) {
        float4 t = *(float4*)(base + (size_t)c * HW);
        t.x *= inv.x; t.y *= inv.y; t.z *= inv.z; t.w *= inv.w;
        *(float4*)(base + (size_t)c * HW) = t;
    }
    *(float4*)wb = make_float4(w.x > 0.f ? 1.f : 0.f, w.y > 0.f ? 1.f : 0.f,
                               w.z > 0.f ? 1.f : 0.f, w.w > 0.f ? 1.f : 0.f);
}

extern "C" void kernel_launch(void* const* d_in, const int* in_sizes, int n_in,
                              void* d_out, int out_size, void* d_ws, size_t ws_size,
                              hipStream_t stream) {
    const float* src = (const float*)d_in[0];    // (4,3,720,1280) fp32
    const float* flow = (const float*)d_in[1];   // (4,2,720,1280) fp32
    float* out = (float*)d_out;                  // img (4,3,HW) ++ mask (4,1,HW)
    int* olist = (int*)d_ws;                     // [0]=count, entries from int[4]
    const int ocap = (int)min((ws_size - 16) / 8, (size_t)1 << 20);

    (void)hipMemsetAsync(d_ws, 0, 16, stream);   // zero the outlier counter

    dim3 grid(W_IMG / TW, (H_IMG + TH - 1) / TH, B_N);   // 20 x 12 x 4
    gather_kernel<<<grid, 256, 0, stream>>>(src, flow, out, olist, ocap);

    outlier_kernel<<<8, 256, 0, stream>>>(src, flow, out, olist, ocap);

    const int n4 = B_N * HW / 4;
    finalize_kernel<<<(n4 + 255) / 256, 256, 0, stream>>>(out);
}

// Round 7
// 389.844 us; speedup vs baseline: 1.3614x; 1.3614x over previous
//
#include <hip/hip_runtime.h>

// Problem constants
constexpr int B_N = 4;
constexpr int C_N = 3;
constexpr int H_IMG = 720;
constexpr int W_IMG = 1280;
constexpr int HW = H_IMG * W_IMG;
// KERNEL_RADIUS=4, KERNEL_SIGMA2=0.5 -> w = exp(-d2)

// Gather tiling: block owns 64x64 targets; thread owns 8 (x) * 2 (y) targets.
constexpr int TW = 64, TH = 64;
constexpr int HALO = 7;                 // R(4) + flow slack (3.5)
constexpr int CW = TW + 2 * HALO;       // 78
constexpr int CH = TH + 2 * HALO;       // 78
constexpr int PITCH = 78;               // even (aligned h2 pairs), odd word-stride
constexpr int PLANE = CH * PITCH;       // 6084 halfs/plane; 5 planes = 60.8 KB
constexpr float FLOW_MAX = 3.5f;
constexpr float LOG2E = 1.44269504f;
constexpr float MARKER = -30.0f;        // all weights underflow to 0, temps finite

typedef _Float16 h2 __attribute__((ext_vector_type(2)));
#define PKRTZ(a, b) __builtin_bit_cast(h2, __builtin_amdgcn_cvt_pkrtz((a), (b)))

// Forward-chain ratio constants: r_i = G * e^{-(2i+1)}, i = 0..6
__constant__ float CE[7] = {
    0.36787944117144233f,   // e^-1
    0.049787068367863944f,  // e^-3
    0.006737946999085467f,  // e^-5
    0.0009118819655545162f, // e^-7
    0.00012340980408667956f,// e^-9
    1.670170079024566e-05f, // e^-11
    2.2603294069810542e-06f // e^-13
};

__global__ __launch_bounds__(256, 2)
void gather_kernel(const float* __restrict__ src, const float* __restrict__ flow,
                   float* __restrict__ out) {
    __shared__ _Float16 Up[PLANE], Vp[PLANE], P0[PLANE], P1[PLANE], P2[PLANE];

    const int b = blockIdx.z;
    const int tx0 = blockIdx.x * TW;
    const int ty0 = blockIdx.y * TH;
    const int cx0 = tx0 - HALO, cy0 = ty0 - HALO;

    const float* __restrict__ up = flow + (size_t)(b * 2) * HW;
    const float* __restrict__ vp = up + HW;
    const float* __restrict__ sp = src + (size_t)(b * 3) * HW;

    // Stage coverage as 5 f16 planes. Invalid / outlier cells -> MARKER
    // (their weights underflow to exactly 0; outliers were pre-splatted).
    for (int idx = threadIdx.x; idx < CH * CW; idx += 256) {
        const int cr = idx / CW, cx = idx - cr * CW;
        const int gx = cx0 + cx, gy = cy0 + cr;
        float u = MARKER, v = MARKER, s0 = 0.f, s1 = 0.f, s2 = 0.f;
        if (gx >= 0 && gx < W_IMG && gy >= 0 && gy < H_IMG) {
            const int g = gy * W_IMG + gx;
            const float uu = up[g], vv = vp[g];
            if (fabsf(uu) <= FLOW_MAX && fabsf(vv) <= FLOW_MAX) {
                u = uu; v = vv;
                s0 = sp[g]; s1 = sp[HW + g]; s2 = sp[2 * HW + g];
            }
        }
        const int l = cr * PITCH + cx;
        Up[l] = (_Float16)u; Vp[l] = (_Float16)v;
        P0[l] = (_Float16)s0; P1[l] = (_Float16)s1; P2[l] = (_Float16)s2;
    }
    __syncthreads();

    const int xg = threadIdx.x & 7;     // 8 x-groups of 8 targets
    const int yg = threadIdx.x >> 3;    // 32 row-pairs
    const int ty_a = ty0 + 2 * yg;

    float aW[2][8], a0[2][8], a1[2][8], a2[2][8];
#pragma unroll
    for (int j = 0; j < 2; ++j)
#pragma unroll
        for (int i = 0; i < 8; ++i) { aW[j][i] = 0.f; a0[j][i] = 0.f;
                                      a1[j][i] = 0.f; a2[j][i] = 0.f; }

    for (int oy = 0; oy < 16; ++oy) {
        const float Cy = (float)(oy - 7);
        const int lrow = (2 * yg + oy) * PITCH + 8 * xg;   // even
#pragma unroll
        for (int oxp = 0; oxp < 11; ++oxp) {               // 22 cells = 11 pairs
            const int l = lrow + 2 * oxp;
            const h2 u2 = *(const h2*)(Up + l);
            const h2 v2 = *(const h2*)(Vp + l);
            const h2 s02 = *(const h2*)(P0 + l);
            const h2 s12 = *(const h2*)(P1 + l);
            const h2 s22 = *(const h2*)(P2 + l);
            const float uA = (float)u2.x, uB = (float)u2.y;
            const float vA = (float)v2.x, vB = (float)v2.y;

            // ---- x chains, forward-only: dx0 = cell_x - target0_x + u ----
            const float dx0A = uA + (float)(2 * oxp - 7);
            const float dx0B = uB + (float)(2 * oxp - 6);
            const float aLA = dx0A * (-LOG2E);
            const float aLB = dx0B * (-LOG2E);
            const float w0A = __builtin_amdgcn_exp2f(aLA * dx0A);  // exp(-dx0^2)
            const float w0B = __builtin_amdgcn_exp2f(aLB * dx0B);
            const float sA = aLA + aLA, sB = aLB + aLB;
            const float GA = __builtin_amdgcn_exp2f(-sA);          // exp(2*dx0)
            const float GB = __builtin_amdgcn_exp2f(-sB);

            float wA[8], wB[8];
            wA[0] = w0A; wB[0] = w0B;
#pragma unroll
            for (int i = 0; i < 7; ++i) {
                wA[i + 1] = wA[i] * (GA * CE[i]);
                wB[i + 1] = wB[i] * (GB * CE[i]);
            }

            h2 w2[8];
#pragma unroll
            for (int i = 0; i < 8; ++i)
                w2[i] = PKRTZ(wA[i], wB[i]);

            // ---- y weights (rows a,b), direct exps ----
            const float dyA = vA + Cy, dyB = vB + Cy;
            const float dybA = dyA - 1.f, dybB = dyB - 1.f;
            const float bLA = dyA * (-LOG2E), bLB = dyB * (-LOG2E);
            const float cLA = dybA * (-LOG2E), cLB = dybB * (-LOG2E);
            const float eyaA = __builtin_amdgcn_exp2f(bLA * dyA);
            const float eyaB = __builtin_amdgcn_exp2f(bLB * dyB);
            const float eybA = __builtin_amdgcn_exp2f(cLA * dybA);
            const float eybB = __builtin_amdgcn_exp2f(cLB * dybB);

            const h2 eya2 = PKRTZ(eyaA, eyaB);
            const h2 eyb2 = PKRTZ(eybA, eybB);
            const h2 z0a = s02 * eya2, z0b = s02 * eyb2;
            const h2 z1a = s12 * eya2, z1b = s12 * eyb2;
            const h2 z2a = s22 * eya2, z2b = s22 * eyb2;

#pragma unroll
            for (int i = 0; i < 8; ++i) {
                aW[0][i] = __builtin_amdgcn_fdot2(w2[i], eya2, aW[0][i], false);
                aW[1][i] = __builtin_amdgcn_fdot2(w2[i], eyb2, aW[1][i], false);
                a0[0][i] = __builtin_amdgcn_fdot2(w2[i], z0a, a0[0][i], false);
                a0[1][i] = __builtin_amdgcn_fdot2(w2[i], z0b, a0[1][i], false);
                a1[0][i] = __builtin_amdgcn_fdot2(w2[i], z1a, a1[0][i], false);
                a1[1][i] = __builtin_amdgcn_fdot2(w2[i], z1b, a1[1][i], false);
                a2[0][i] = __builtin_amdgcn_fdot2(w2[i], z2a, a2[0][i], false);
                a2[1][i] = __builtin_amdgcn_fdot2(w2[i], z2b, a2[1][i], false);
            }
        }
    }

    // Fused epilogue: add pre-splatted outlier contributions (already in out),
    // divide by (w+eps), write final image + mask. No finalize kernel.
    float* __restrict__ wI = out;
    float* __restrict__ wb = out + (size_t)B_N * C_N * HW;
    const int gx0 = tx0 + 8 * xg;
#pragma unroll
    for (int j = 0; j < 2; ++j) {
        const int ty = ty_a + j;
        if (ty >= H_IMG) continue;
        const int tb = ty * W_IMG + gx0;              // 16B-aligned
        float* p0 = wI + (size_t)(b * 3 + 0) * HW + tb;
        float* p1 = wI + (size_t)(b * 3 + 1) * HW + tb;
        float* p2 = wI + (size_t)(b * 3 + 2) * HW + tb;
        float* pw = wb + (size_t)b * HW + tb;
#pragma unroll
        for (int h = 0; h < 2; ++h) {                 // two float4 halves
            const float4 q0 = *(float4*)(p0 + 4 * h);
            const float4 q1 = *(float4*)(p1 + 4 * h);
            const float4 q2 = *(float4*)(p2 + 4 * h);
            const float4 qw = *(float4*)(pw + 4 * h);
            float wv[4] = {qw.x + aW[j][4*h+0], qw.y + aW[j][4*h+1],
                           qw.z + aW[j][4*h+2], qw.w + aW[j][4*h+3]};
            float inv[4];
#pragma unroll
            for (int t = 0; t < 4; ++t) inv[t] = 1.0f / (wv[t] + 1e-8f);
            *(float4*)(p0 + 4 * h) = make_float4(
                (q0.x + a0[j][4*h+0]) * inv[0], (q0.y + a0[j][4*h+1]) * inv[1],
                (q0.z + a0[j][4*h+2]) * inv[2], (q0.w + a0[j][4*h+3]) * inv[3]);
            *(float4*)(p1 + 4 * h) = make_float4(
                (q1.x + a1[j][4*h+0]) * inv[0], (q1.y + a1[j][4*h+1]) * inv[1],
                (q1.z + a1[j][4*h+2]) * inv[2], (q1.w + a1[j][4*h+3]) * inv[3]);
            *(float4*)(p2 + 4 * h) = make_float4(
                (q2.x + a2[j][4*h+0]) * inv[0], (q2.y + a2[j][4*h+1]) * inv[1],
                (q2.z + a2[j][4*h+2]) * inv[2], (q2.w + a2[j][4*h+3]) * inv[3]);
            *(float4*)(pw + 4 * h) = make_float4(
                wv[0] > 0.f ? 1.f : 0.f, wv[1] > 0.f ? 1.f : 0.f,
                wv[2] > 0.f ? 1.f : 0.f, wv[3] > 0.f ? 1.f : 0.f);
        }
    }
}

// Exact splat for rare sources with |u|>3.5 or |v|>3.5 (~9e-4 of pixels).
// Runs BEFORE gather on the zeroed out buffer; gather adds these in.
__global__ __launch_bounds__(256)
void outlier_kernel(const float* __restrict__ src, const float* __restrict__ flow,
                    float* __restrict__ out) {
    const int n4 = B_N * HW / 4;
    const int i4 = blockIdx.x * 256 + threadIdx.x;
    if (i4 >= n4) return;
    const int per_b = HW / 4;
    const int b = i4 / per_b;
    const int g0 = (i4 - b * per_b) * 4;
    const float* __restrict__ up = flow + (size_t)(b * 2) * HW;
    const float4 u4 = *(const float4*)(up + g0);
    const float4 v4 = *(const float4*)(up + HW + g0);
    const float um = fmaxf(fmaxf(fabsf(u4.x), fabsf(u4.y)), fmaxf(fabsf(u4.z), fabsf(u4.w)));
    const float vm = fmaxf(fmaxf(fabsf(v4.x), fabsf(v4.y)), fmaxf(fabsf(v4.z), fabsf(v4.w)));
    if (um <= FLOW_MAX && vm <= FLOW_MAX) return;

    const float uu[4] = {u4.x, u4.y, u4.z, u4.w};
    const float vv[4] = {v4.x, v4.y, v4.z, v4.w};
    const float* __restrict__ sp = src + (size_t)(b * 3) * HW;
    float* __restrict__ wI = out;
    float* __restrict__ wb = out + (size_t)B_N * C_N * HW;

    for (int k = 0; k < 4; ++k) {
        const float u = uu[k], v = vv[k];
        if (fabsf(u) <= FLOW_MAX && fabsf(v) <= FLOW_MAX) continue;
        const int g = g0 + k;
        const int x = g % W_IMG, y = g / W_IMG;
        const float px = (float)x + u, py = (float)y + v;
        if (!(px > -6.f && px < (float)W_IMG + 5.f &&
              py > -6.f && py < (float)H_IMG + 5.f)) continue;

        const float bxf = floorf(px), byf = floorf(py);
        const int bx = (int)bxf, by = (int)byf;
        const float s0 = sp[g], s1 = sp[HW + g], s2 = sp[2 * HW + g];

        for (int dyi = -4; dyi <= 4; ++dyi) {
            const int tyy = by + dyi;
            if (tyy < 0 || tyy >= H_IMG) continue;
            const float dyf = (byf + (float)dyi) - py;
            const float dy2 = dyf * dyf;
            for (int dxi = -4; dxi <= 4; ++dxi) {
                const int txx = bx + dxi;
                if (txx < 0 || txx >= W_IMG) continue;
                const float dxf = (bxf + (float)dxi) - px;
                const float d2 = fmaf(dxf, dxf, dy2);
                if (d2 > 16.f) continue;
                const float w = __expf(-d2);
                const int t = tyy * W_IMG + txx;
                atomicAdd(&wb[(size_t)b * HW + t], w);
                atomicAdd(&wI[(size_t)(b * 3 + 0) * HW + t], w * s0);
                atomicAdd(&wI[(size_t)(b * 3 + 1) * HW + t], w * s1);
                atomicAdd(&wI[(size_t)(b * 3 + 2) * HW + t], w * s2);
            }
        }
    }
}

extern "C" void kernel_launch(void* const* d_in, const int* in_sizes, int n_in,
                              void* d_out, int out_size, void* d_ws, size_t ws_size,
                              hipStream_t stream) {
    const float* src = (const float*)d_in[0];    // (4,3,720,1280) fp32
    const float* flow = (const float*)d_in[1];   // (4,2,720,1280) fp32
    float* out = (float*)d_out;                  // img (4,3,HW) ++ mask (4,1,HW)

    // 1) zero accumulators (out is poisoned 0xAA before every timed launch)
    (void)hipMemsetAsync(d_out, 0, (size_t)out_size * sizeof(float), stream);

    // 2) pre-splat rare large-flow sources with global atomics
    const int n4 = B_N * HW / 4;
    outlier_kernel<<<(n4 + 255) / 256, 256, 0, stream>>>(src, flow, out);

    // 3) gather everything else; fused add-prior + divide + mask epilogue
    dim3 grid(W_IMG / TW, (H_IMG + TH - 1) / TH, B_N);   // 20 x 12 x 4
    gather_kernel<<<grid, 256, 0, stream>>>(src, flow, out);
}